// Round 3
// baseline (420.666 us; speedup 1.0000x reference)
//
#include <hip/hip_runtime.h>
#include <math.h>

#define BB 4
#define CC 64
#define OO 64
#define HH 128
#define WWD 128
#define HWP (HH*WWD)   // 16384

typedef short bf16x8 __attribute__((ext_vector_type(8)));
typedef float f32x4  __attribute__((ext_vector_type(4)));
typedef float f32x2  __attribute__((ext_vector_type(2)));

__device__ __forceinline__ unsigned short bf16_rne(float f) {
    unsigned u = __float_as_uint(f);
    u += 0x7fffu + ((u >> 16) & 1u);
    return (unsigned short)(u >> 16);
}
__device__ __forceinline__ float bf16_tof(unsigned short h) {
    return __uint_as_float((unsigned)h << 16);
}
// unaligned-8B-capable float2 load (align 4): emits global_load_dwordx2
__device__ __forceinline__ f32x2 ld2(const float* p) {
    f32x2 r; __builtin_memcpy(&r, p, 2 * sizeof(float)); return r;
}
// 16B bf16 fragment load straight from global (16B-aligned by construction)
__device__ __forceinline__ bf16x8 ldw16(const unsigned short* p) {
    bf16x8 r; __builtin_memcpy(&r, p, 16); return r;
}

// ---------------------------------------------------------------------------
// Kernel 1: W[o][c][3][3] fp32 -> Whi/Wlo[k][o][c] bf16 (hi/lo split) for
// both layers. grid: 288 x 256 = 73728 = 2 * 64*64*9
// ---------------------------------------------------------------------------
__global__ __launch_bounds__(256) void wtrans_kernel(
    const float* __restrict__ W1, const float* __restrict__ W2,
    unsigned short* __restrict__ Wh1, unsigned short* __restrict__ Wl1,
    unsigned short* __restrict__ Wh2, unsigned short* __restrict__ Wl2)
{
    int idx = blockIdx.x * 256 + threadIdx.x;
    const int n = OO * CC * 9;           // 36864
    const float* src;
    unsigned short *dh, *dl;
    if (idx >= n) { src = W2; dh = Wh2; dl = Wl2; idx -= n; }
    else          { src = W1; dh = Wh1; dl = Wl1; }
    // dst index = (k*64 + o)*64 + c
    int c = idx & 63;
    int o = (idx >> 6) & 63;
    int k = idx >> 12;
    float w = src[(o * CC + c) * 9 + k];
    unsigned short hi = bf16_rne(w);
    unsigned short lo = bf16_rne(w - bf16_tof(hi));
    dh[idx] = hi;
    dl[idx] = lo;
}

// ---------------------------------------------------------------------------
// Per-tap bilinear coordinate state (one pixel per lane).
// off0/off1: element offsets of the top/bottom sample rows in a channel plane.
// ---------------------------------------------------------------------------
struct TapC {
    float w00, w01, w10, w11;
    int off0, off1;
    int xhi;
};

template<int DY, int DX>
__device__ __forceinline__ TapC mk_coords(int y, int xg, float fy, float fx,
                                          float rh, float rw)
{
    TapC C; C.w00 = C.w01 = C.w10 = C.w11 = 0.f; C.off0 = C.off1 = 0; C.xhi = 0;
    if (DY == 0 && DX == 0) {
        C.off0 = y * WWD + xg;
    } else if (DY == 0) {          // row-edge: ty == 0 exactly
        float xs = fx + (float)DX * rw;
        float x0f = floorf(xs);
        float tx = xs - x0f;
        int ix0 = min(max((int)x0f, 0), WWD - 1);
        int ix0c = min(ix0, WWD - 2);
        C.xhi = (ix0 == WWD - 1);
        C.w00 = 1.f - tx; C.w01 = tx;
        C.off0 = y * WWD + ix0c;
    } else if (DX == 0) {          // col-edge: tx == 0 exactly
        float ys = fy + (float)DY * rh;
        float y0f = floorf(ys);
        float ty = ys - y0f;
        int iy0 = min(max((int)y0f, 0), HH - 1);
        int iy1 = min(iy0 + 1, HH - 1);
        C.w00 = 1.f - ty; C.w10 = ty;
        C.off0 = iy0 * WWD + xg;
        C.off1 = iy1 * WWD + xg;
    } else {                       // corner
        float ys = fy + (float)DY * rh;
        float xs = fx + (float)DX * rw;
        float y0f = floorf(ys), x0f = floorf(xs);
        float ty = ys - y0f, tx = xs - x0f;
        int iy0 = min(max((int)y0f, 0), HH - 1);
        int iy1 = min(iy0 + 1, HH - 1);
        int ix0 = min(max((int)x0f, 0), WWD - 1);
        int ix0c = min(ix0, WWD - 2);
        C.xhi = (ix0 == WWD - 1);
        C.w00 = (1.f - ty) * (1.f - tx);
        C.w01 = (1.f - ty) * tx;
        C.w10 = ty * (1.f - tx);
        C.w11 = ty * tx;
        C.off0 = iy0 * WWD + ix0c;
        C.off1 = iy1 * WWD + ix0c;
    }
    return C;
}

// Issue the raw gather loads for 8 channels (one K-half) of this lane's pixel.
// xq = per-lane channel-run base (xbase + (quad*8 + ks*32)*HWP).
template<int DY, int DX>
__device__ __forceinline__ void gather_half(
    const float* __restrict__ xq, const TapC& C,
    float (&g0)[8], float (&g1)[8], float (&g2)[8], float (&g3)[8])
{
    if (DY == 0 && DX == 0) {
#pragma unroll
        for (int i = 0; i < 8; ++i) g0[i] = xq[C.off0 + i * HWP];
    } else if (DY == 0) {
#pragma unroll
        for (int i = 0; i < 8; ++i) {
            f32x2 p = ld2(xq + C.off0 + i * HWP);
            g0[i] = p.x; g1[i] = p.y;
        }
    } else if (DX == 0) {
#pragma unroll
        for (int i = 0; i < 8; ++i) {
            g0[i] = xq[C.off0 + i * HWP];
            g2[i] = xq[C.off1 + i * HWP];
        }
    } else {
#pragma unroll
        for (int i = 0; i < 8; ++i) {
            f32x2 pt = ld2(xq + C.off0 + i * HWP);
            f32x2 pb = ld2(xq + C.off1 + i * HWP);
            g0[i] = pt.x; g1[i] = pt.y;
            g2[i] = pb.x; g3[i] = pb.y;
        }
    }
}

// Combine gathered values -> bf16 hi/lo B-fragments (channels j=0..7).
template<int DY, int DX>
__device__ __forceinline__ void combine_half(
    const TapC& C,
    const float (&g0)[8], const float (&g1)[8],
    const float (&g2)[8], const float (&g3)[8],
    bf16x8& bh, bf16x8& bl)
{
    union { unsigned short h[8]; bf16x8 v; } uh, ul;
#pragma unroll
    for (int i = 0; i < 8; ++i) {
        float s;
        if (DY == 0 && DX == 0) {
            s = g0[i];
        } else if (DY == 0) {
            float a0 = C.xhi ? g1[i] : g0[i];
            s = C.w00 * a0 + C.w01 * g1[i];
        } else if (DX == 0) {
            s = C.w00 * g0[i] + C.w10 * g2[i];
        } else {
            float t0 = C.xhi ? g1[i] : g0[i];
            float b0 = C.xhi ? g3[i] : g2[i];
            s = C.w00 * t0 + C.w01 * g1[i] + C.w10 * b0 + C.w11 * g3[i];
        }
        unsigned short hs = bf16_rne(s);
        uh.h[i] = hs;
        ul.h[i] = bf16_rne(s - bf16_tof(hs));
    }
    bh = uh.v; bl = ul.v;
}

// ---------------------------------------------------------------------------
// Kernel 2: fused offsets-conv + arconv. ZERO LDS, ZERO barriers.
// grid: 1024 blocks x 256 threads (4 independent waves). XCD-chunked swizzle.
// Wave wv owns pixels p0 + wv*16 .. +16 (N-split). Lane l = quad*16 + nidx:
//   pixel = wv*16 + nidx, channel runs quad*8..+8 and quad*8+32..+40 --
//   exactly the mfma_16x16x32_bf16 B-fragment layout, gathered DIRECTLY from
//   global (no LDS staging, no redistribution). A-fragments (weights) are a
//   fixed strided pattern in [k][O][C], loaded straight from global (L1-hot:
//   identical addresses for all waves/blocks).
// Phase A (rf conv) is also barrier-free: channel split across quads +
//   2x shfl_xor reduce, sigmoid computed redundantly per lane.
// Tap loop: 18 half-tap stages, gathers pipelined one stage ahead (ILP),
//   plus 4 waves/SIMD TLP. hi/lo 3-product MFMA (fp32-accurate), bit-identical
//   fragment contents to the previous LDS-staged version.
// mode 1: out = relu(acc + bias). mode 2: out = resid + acc + bias.
// ---------------------------------------------------------------------------
__global__ __launch_bounds__(256, 4) void arconv_kernel(
    const float*          __restrict__ xin,   // [B,C,H,W]
    const unsigned short* __restrict__ Whi,   // [9][O][C] bf16 hi
    const unsigned short* __restrict__ Wlo,   // [9][O][C] bf16 lo
    const float*          __restrict__ bias,
    const float*          __restrict__ woff,  // [2][C][3][3]
    const float*          __restrict__ boff,  // [2]
    const int* __restrict__ lo_p, const int* __restrict__ hi_p,
    const float* __restrict__ resid,
    float* __restrict__ out, int mode)
{
    int t    = threadIdx.x;
    int bid  = blockIdx.x;
    // XCD-chunked swizzle (R1: FETCH 123MB -> 9.6MB).
    int blk  = ((bid & 7) << 7) | (bid >> 3);
    int b    = blk >> 8;
    int tile = blk & 255;
    int p0   = tile * 64;
    int y    = p0 >> 7;
    int xb   = p0 & 127;

    int lane = t & 63;
    int wv   = t >> 6;
    int nidx = lane & 15;
    int quad = lane >> 4;
    int xg   = xb + wv * 16 + nidx;       // absolute x of this lane's pixel
    float fy = (float)y;
    float fx = (float)xg;

    const float* xbase = xin + (size_t)b * CC * HWP;

    // ---- phase A: offsets conv, barrier-free ----
    // lane covers channels quad*16..+16 of ITS pixel; reduce across quads.
    float a0 = 0.f, a1 = 0.f;
    {
#pragma unroll 4
        for (int ci = 0; ci < 16; ++ci) {
            int c = quad * 16 + ci;
            const float* xc = xbase + (size_t)c * HWP;
            const float* w0 = woff + c * 9;
            const float* w1 = woff + (CC + c) * 9;
#pragma unroll
            for (int ky = 0; ky < 3; ++ky) {
                int yy = y + ky - 1;
                bool yok = (yy >= 0) && (yy < HH);
#pragma unroll
                for (int kx = 0; kx < 3; ++kx) {
                    int xx = xg + kx - 1;
                    float v = 0.f;
                    if (yok && xx >= 0 && xx < WWD) v = xc[yy * WWD + xx];
                    a0 = fmaf(v, w0[ky * 3 + kx], a0);
                    a1 = fmaf(v, w1[ky * 3 + kx], a1);
                }
            }
        }
        a0 += __shfl_xor(a0, 16); a0 += __shfl_xor(a0, 32);
        a1 += __shfl_xor(a1, 16); a1 += __shfl_xor(a1, 32);
    }
    float flo = (float)lo_p[0];
    float fhi = (float)hi_p[0];
    float rh = (flo + (fhi - flo) / (1.f + expf(-(a0 + boff[0])))) * 0.5f;
    float rw = (flo + (fhi - flo) / (1.f + expf(-(a1 + boff[1])))) * 0.5f;

    // ---- tap loop ----
    const float* xq0 = xbase + (size_t)(quad * 8) * HWP;        // ks=0 channels
    const float* xq1 = xq0 + (size_t)32 * HWP;                  // ks=1 channels
    const int fragbase = nidx * CC + quad * 8;                  // A-frag offset

    f32x4 acc0 = {}, acc1 = {}, acc2 = {}, acc3 = {};
    float gA0[8], gA1[8], gA2[8], gA3[8];   // gather set for ks=0 of cur tap
    float gB0[8], gB1[8], gB2[8], gB3[8];   // gather set for ks=1 of cur tap
    TapC C;

#define MFMA(a, bfr, c) __builtin_amdgcn_mfma_f32_16x16x32_bf16(a, bfr, c, 0, 0, 0)
#define MFMA_BLOCK(WH, WL, bh, bl) do { \
        bf16x8 ah0 = ldw16(WH),        al0 = ldw16(WL); \
        bf16x8 ah1 = ldw16(WH + 1024), al1 = ldw16(WL + 1024); \
        bf16x8 ah2 = ldw16(WH + 2048), al2 = ldw16(WL + 2048); \
        bf16x8 ah3 = ldw16(WH + 3072), al3 = ldw16(WL + 3072); \
        acc0 = MFMA(ah0, bh, acc0); acc0 = MFMA(al0, bh, acc0); acc0 = MFMA(ah0, bl, acc0); \
        acc1 = MFMA(ah1, bh, acc1); acc1 = MFMA(al1, bh, acc1); acc1 = MFMA(ah1, bl, acc1); \
        acc2 = MFMA(ah2, bh, acc2); acc2 = MFMA(al2, bh, acc2); acc2 = MFMA(ah2, bl, acc2); \
        acc3 = MFMA(ah3, bh, acc3); acc3 = MFMA(al3, bh, acc3); acc3 = MFMA(ah3, bl, acc3); \
    } while (0)

#define TAP(K, DYc, DXc, NDY, NDX, ISLAST) \
    { \
        /* stage ks=0: issue ks=1 gathers into gB, consume gA */ \
        gather_half<DYc, DXc>(xq1, C, gB0, gB1, gB2, gB3); \
        { \
            bf16x8 bh, bl; \
            combine_half<DYc, DXc>(C, gA0, gA1, gA2, gA3, bh, bl); \
            const unsigned short* whk = Whi + (K) * OO * CC + fragbase; \
            const unsigned short* wlk = Wlo + (K) * OO * CC + fragbase; \
            MFMA_BLOCK(whk, wlk, bh, bl); \
        } \
        /* stage ks=1: compute next coords, issue next ks=0 into gA, consume gB */ \
        { \
            TapC Cn = C; \
            if (!(ISLAST)) { \
                Cn = mk_coords<NDY, NDX>(y, xg, fy, fx, rh, rw); \
                gather_half<NDY, NDX>(xq0, Cn, gA0, gA1, gA2, gA3); \
            } \
            bf16x8 bh, bl; \
            combine_half<DYc, DXc>(C, gB0, gB1, gB2, gB3, bh, bl); \
            const unsigned short* whk = Whi + (K) * OO * CC + fragbase + 32; \
            const unsigned short* wlk = Wlo + (K) * OO * CC + fragbase + 32; \
            MFMA_BLOCK(whk, wlk, bh, bl); \
            C = Cn; \
        } \
    }

    // prologue: stage tap 0, ks=0
    C = mk_coords<-1, -1>(y, xg, fy, fx, rh, rw);
    gather_half<-1, -1>(xq0, C, gA0, gA1, gA2, gA3);

    TAP(0, -1, -1, -1,  0, 0)
    TAP(1, -1,  0, -1,  1, 0)
    TAP(2, -1,  1,  0, -1, 0)
    TAP(3,  0, -1,  0,  0, 0)
    TAP(4,  0,  0,  0,  1, 0)
    TAP(5,  0,  1,  1, -1, 0)
    TAP(6,  1, -1,  1,  0, 0)
    TAP(7,  1,  0,  1,  1, 0)
    TAP(8,  1,  1,  0,  0, 1)

#undef TAP
#undef MFMA_BLOCK
#undef MFMA

    // epilogue: o = mt*16 + quad*4 + r, pixel = p0 + wv*16 + nidx
    int px = p0 + wv * 16 + nidx;
#define EPI(MT, ACCV) do { \
        _Pragma("unroll") \
        for (int r = 0; r < 4; ++r) { \
            int o = (MT) * 16 + quad * 4 + r; \
            float v = ACCV[r] + bias[o]; \
            size_t idx = (size_t)(b * OO + o) * HWP + px; \
            if (mode == 1) v = fmaxf(v, 0.f); \
            else           v += resid[idx]; \
            out[idx] = v; \
        } \
    } while (0)
    EPI(0, acc0); EPI(1, acc1); EPI(2, acc2); EPI(3, acc3);
#undef EPI
}

// ---------------------------------------------------------------------------
extern "C" void kernel_launch(void* const* d_in, const int* in_sizes, int n_in,
                              void* d_out, int out_size, void* d_ws, size_t ws_size,
                              hipStream_t stream) {
    const float* x      = (const float*)d_in[0];
    const float* w_off1 = (const float*)d_in[1];
    const float* b_off1 = (const float*)d_in[2];
    const float* W1     = (const float*)d_in[3];
    const float* b1     = (const float*)d_in[4];
    const float* w_off2 = (const float*)d_in[5];
    const float* b_off2 = (const float*)d_in[6];
    const float* W2     = (const float*)d_in[7];
    const float* b2     = (const float*)d_in[8];
    const int*   lo_p   = (const int*)d_in[10];
    const int*   hi_p   = (const int*)d_in[11];
    float* outp = (float*)d_out;

    float* wsf = (float*)d_ws;
    float* t1  = wsf;                               // B*C*HW f32
    unsigned short* Wh1 = (unsigned short*)(t1 + (size_t)BB * CC * HWP);
    unsigned short* Wl1 = Wh1 + OO * CC * 9;        // 36864 each
    unsigned short* Wh2 = Wl1 + OO * CC * 9;
    unsigned short* Wl2 = Wh2 + OO * CC * 9;

    // 1. transpose+split both weight tensors
    wtrans_kernel<<<288, 256, 0, stream>>>(W1, W2, Wh1, Wl1, Wh2, Wl2);

    // 2. layer 1: fused offsets + arconv + relu -> t1
    arconv_kernel<<<1024, 256, 0, stream>>>(x, Wh1, Wl1, b1, w_off1, b_off1,
                                            lo_p, hi_p, nullptr, t1, 1);

    // 3. layer 2: fused offsets + arconv + residual -> out
    arconv_kernel<<<1024, 256, 0, stream>>>(t1, Wh2, Wl2, b2, w_off2, b_off2,
                                            lo_p, hi_p, x, outp, 2);
}

// Round 4
// 335.128 us; speedup vs baseline: 1.2552x; 1.2552x over previous
//
#include <hip/hip_runtime.h>
#include <math.h>

#define BB 4
#define CC 64
#define OO 64
#define HH 128
#define WWD 128
#define HWP (HH*WWD)   // 16384

typedef short bf16x8 __attribute__((ext_vector_type(8)));
typedef float f32x4  __attribute__((ext_vector_type(4)));
typedef float f32x2  __attribute__((ext_vector_type(2)));

__device__ __forceinline__ unsigned short bf16_rne(float f) {
    unsigned u = __float_as_uint(f);
    u += 0x7fffu + ((u >> 16) & 1u);
    return (unsigned short)(u >> 16);
}
__device__ __forceinline__ float bf16_tof(unsigned short h) {
    return __uint_as_float((unsigned)h << 16);
}
// unaligned-8B-capable float2 load (align 4): emits global_load_dwordx2
__device__ __forceinline__ f32x2 ld2(const float* p) {
    f32x2 r; __builtin_memcpy(&r, p, 2 * sizeof(float)); return r;
}
// 16B bf16 fragment load straight from global (16B-aligned by construction)
__device__ __forceinline__ bf16x8 ldw16(const unsigned short* p) {
    bf16x8 r; __builtin_memcpy(&r, p, 16); return r;
}

// ---------------------------------------------------------------------------
// Kernel 1: W[o][c][3][3] fp32 -> Whi/Wlo[k][o][c] bf16 (hi/lo split) for
// both layers. grid: 288 x 256 = 73728 = 2 * 64*64*9
// ---------------------------------------------------------------------------
__global__ __launch_bounds__(256) void wtrans_kernel(
    const float* __restrict__ W1, const float* __restrict__ W2,
    unsigned short* __restrict__ Wh1, unsigned short* __restrict__ Wl1,
    unsigned short* __restrict__ Wh2, unsigned short* __restrict__ Wl2)
{
    int idx = blockIdx.x * 256 + threadIdx.x;
    const int n = OO * CC * 9;           // 36864
    const float* src;
    unsigned short *dh, *dl;
    if (idx >= n) { src = W2; dh = Wh2; dl = Wl2; idx -= n; }
    else          { src = W1; dh = Wh1; dl = Wl1; }
    // dst index = (k*64 + o)*64 + c
    int c = idx & 63;
    int o = (idx >> 6) & 63;
    int k = idx >> 12;
    float w = src[(o * CC + c) * 9 + k];
    unsigned short hi = bf16_rne(w);
    unsigned short lo = bf16_rne(w - bf16_tof(hi));
    dh[idx] = hi;
    dl[idx] = lo;
}

// ---------------------------------------------------------------------------
// Per-tap bilinear coordinate state (one pixel per lane).
// off0/off1: element offsets of the top/bottom sample rows in a channel plane.
// x-clamp at 127 is folded into the weights (w01 += w00, w00 = 0), so the
// combine needs no selects and TapC needs no flag.
// ---------------------------------------------------------------------------
struct TapC {
    float w00, w01, w10, w11;
    int off0, off1;
};

template<int DY, int DX>
__device__ __forceinline__ TapC mk_coords(int y, int xg, float fy, float fx,
                                          float rh, float rw)
{
    TapC C; C.w00 = C.w01 = C.w10 = C.w11 = 0.f; C.off0 = C.off1 = 0;
    if (DY == 0 && DX == 0) {
        C.off0 = y * WWD + xg;
    } else if (DY == 0) {          // row-edge: ty == 0 exactly
        float xs = fx + (float)DX * rw;
        float x0f = floorf(xs);
        float tx = xs - x0f;
        int ix0 = min(max((int)x0f, 0), WWD - 1);
        int ix0c = min(ix0, WWD - 2);
        C.w00 = 1.f - tx; C.w01 = tx;
        if (ix0 == WWD - 1) { C.w01 += C.w00; C.w00 = 0.f; }
        C.off0 = y * WWD + ix0c;
    } else if (DX == 0) {          // col-edge: tx == 0 exactly
        float ys = fy + (float)DY * rh;
        float y0f = floorf(ys);
        float ty = ys - y0f;
        int iy0 = min(max((int)y0f, 0), HH - 1);
        int iy1 = min(iy0 + 1, HH - 1);
        C.w00 = 1.f - ty; C.w10 = ty;
        C.off0 = iy0 * WWD + xg;
        C.off1 = iy1 * WWD + xg;
    } else {                       // corner
        float ys = fy + (float)DY * rh;
        float xs = fx + (float)DX * rw;
        float y0f = floorf(ys), x0f = floorf(xs);
        float ty = ys - y0f, tx = xs - x0f;
        int iy0 = min(max((int)y0f, 0), HH - 1);
        int iy1 = min(iy0 + 1, HH - 1);
        int ix0 = min(max((int)x0f, 0), WWD - 1);
        int ix0c = min(ix0, WWD - 2);
        C.w00 = (1.f - ty) * (1.f - tx);
        C.w01 = (1.f - ty) * tx;
        C.w10 = ty * (1.f - tx);
        C.w11 = ty * tx;
        if (ix0 == WWD - 1) {
            C.w01 += C.w00; C.w00 = 0.f;
            C.w11 += C.w10; C.w10 = 0.f;
        }
        C.off0 = iy0 * WWD + ix0c;
        C.off1 = iy1 * WWD + ix0c;
    }
    return C;
}

// Issue the raw gather loads for 8 channels (one K-half) of this lane's pixel.
// xq = per-lane channel-run base (xbase + (quad*8 + ks*32)*HWP).
template<int DY, int DX>
__device__ __forceinline__ void gather_half(
    const float* __restrict__ xq, const TapC& C,
    float (&g0)[8], float (&g1)[8], float (&g2)[8], float (&g3)[8])
{
    if (DY == 0 && DX == 0) {
#pragma unroll
        for (int i = 0; i < 8; ++i) g0[i] = xq[C.off0 + i * HWP];
    } else if (DY == 0) {
#pragma unroll
        for (int i = 0; i < 8; ++i) {
            f32x2 p = ld2(xq + C.off0 + i * HWP);
            g0[i] = p.x; g1[i] = p.y;
        }
    } else if (DX == 0) {
#pragma unroll
        for (int i = 0; i < 8; ++i) {
            g0[i] = xq[C.off0 + i * HWP];
            g2[i] = xq[C.off1 + i * HWP];
        }
    } else {
#pragma unroll
        for (int i = 0; i < 8; ++i) {
            f32x2 pt = ld2(xq + C.off0 + i * HWP);
            f32x2 pb = ld2(xq + C.off1 + i * HWP);
            g0[i] = pt.x; g1[i] = pt.y;
            g2[i] = pb.x; g3[i] = pb.y;
        }
    }
}

// Combine gathered values -> bf16 hi/lo B-fragments (channels j=0..7).
template<int DY, int DX>
__device__ __forceinline__ void combine_half(
    const TapC& C,
    const float (&g0)[8], const float (&g1)[8],
    const float (&g2)[8], const float (&g3)[8],
    bf16x8& bh, bf16x8& bl)
{
    union { unsigned short h[8]; bf16x8 v; } uh, ul;
#pragma unroll
    for (int i = 0; i < 8; ++i) {
        float s;
        if (DY == 0 && DX == 0) {
            s = g0[i];
        } else if (DY == 0) {
            s = C.w00 * g0[i] + C.w01 * g1[i];
        } else if (DX == 0) {
            s = C.w00 * g0[i] + C.w10 * g2[i];
        } else {
            s = C.w00 * g0[i] + C.w01 * g1[i] + C.w10 * g2[i] + C.w11 * g3[i];
        }
        unsigned short hs = bf16_rne(s);
        uh.h[i] = hs;
        ul.h[i] = bf16_rne(s - bf16_tof(hs));
    }
    bh = uh.v; bl = ul.v;
}

// ---------------------------------------------------------------------------
// Kernel 2: fused offsets-conv + arconv. ZERO LDS, ZERO barriers.
// grid: 1024 blocks x 256 threads (4 independent waves). XCD-chunked swizzle.
// Wave wv owns pixels p0 + wv*16 .. +16 (N-split). Lane l = quad*16 + nidx:
//   pixel = wv*16 + nidx, channel runs quad*8..+8 and quad*8+32..+40 --
//   exactly the mfma_16x16x32_bf16 B-fragment layout, gathered DIRECTLY from
//   global. A-fragments (weights) loaded straight from global (L1/L2-hot).
// __launch_bounds__(256, 2): VGPR cap 256. R3's (256,4) capped at 128 and the
//   allocator spilled the gather arrays to scratch (VGPR=64, WRITE_SIZE
//   117 MB) -- the entire regression. This kernel needs ~150-180 VGPR live.
// Tap loop: 18 half-tap stages, gathers pipelined one stage ahead (ILP),
//   2 waves/SIMD TLP, no barriers anywhere.
// mode 1: out = relu(acc + bias). mode 2: out = resid + acc + bias.
// ---------------------------------------------------------------------------
__global__ __launch_bounds__(256, 2) void arconv_kernel(
    const float*          __restrict__ xin,   // [B,C,H,W]
    const unsigned short* __restrict__ Whi,   // [9][O][C] bf16 hi
    const unsigned short* __restrict__ Wlo,   // [9][O][C] bf16 lo
    const float*          __restrict__ bias,
    const float*          __restrict__ woff,  // [2][C][3][3]
    const float*          __restrict__ boff,  // [2]
    const int* __restrict__ lo_p, const int* __restrict__ hi_p,
    const float* __restrict__ resid,
    float* __restrict__ out, int mode)
{
    int t    = threadIdx.x;
    int bid  = blockIdx.x;
    // XCD-chunked swizzle (R1: FETCH 123MB -> 9.6MB).
    int blk  = ((bid & 7) << 7) | (bid >> 3);
    int b    = blk >> 8;
    int tile = blk & 255;
    int p0   = tile * 64;
    int y    = p0 >> 7;
    int xb   = p0 & 127;

    int lane = t & 63;
    int wv   = t >> 6;
    int nidx = lane & 15;
    int quad = lane >> 4;
    int xg   = xb + wv * 16 + nidx;       // absolute x of this lane's pixel
    float fy = (float)y;
    float fx = (float)xg;

    const float* xbase = xin + (size_t)b * CC * HWP;

    // ---- phase A: offsets conv, barrier-free ----
    // lane covers channels quad*16..+16 of ITS pixel; reduce across quads.
    float a0 = 0.f, a1 = 0.f;
    {
#pragma unroll 4
        for (int ci = 0; ci < 16; ++ci) {
            int c = quad * 16 + ci;
            const float* xc = xbase + (size_t)c * HWP;
            const float* w0 = woff + c * 9;
            const float* w1 = woff + (CC + c) * 9;
#pragma unroll
            for (int ky = 0; ky < 3; ++ky) {
                int yy = y + ky - 1;
                bool yok = (yy >= 0) && (yy < HH);
#pragma unroll
                for (int kx = 0; kx < 3; ++kx) {
                    int xx = xg + kx - 1;
                    float v = 0.f;
                    if (yok && xx >= 0 && xx < WWD) v = xc[yy * WWD + xx];
                    a0 = fmaf(v, w0[ky * 3 + kx], a0);
                    a1 = fmaf(v, w1[ky * 3 + kx], a1);
                }
            }
        }
        a0 += __shfl_xor(a0, 16); a0 += __shfl_xor(a0, 32);
        a1 += __shfl_xor(a1, 16); a1 += __shfl_xor(a1, 32);
    }
    float flo = (float)lo_p[0];
    float fhi = (float)hi_p[0];
    float rh = (flo + (fhi - flo) / (1.f + expf(-(a0 + boff[0])))) * 0.5f;
    float rw = (flo + (fhi - flo) / (1.f + expf(-(a1 + boff[1])))) * 0.5f;

    // ---- tap loop ----
    const float* xq0 = xbase + (size_t)(quad * 8) * HWP;        // ks=0 channels
    const float* xq1 = xq0 + (size_t)32 * HWP;                  // ks=1 channels
    const int fragbase = nidx * CC + quad * 8;                  // A-frag offset

    f32x4 acc0 = {}, acc1 = {}, acc2 = {}, acc3 = {};
    float gA0[8], gA1[8], gA2[8], gA3[8];   // gather set for ks=0 of cur tap
    float gB0[8], gB1[8], gB2[8], gB3[8];   // gather set for ks=1 of cur tap
    TapC C;

#define MFMA(a, bfr, c) __builtin_amdgcn_mfma_f32_16x16x32_bf16(a, bfr, c, 0, 0, 0)
    // Split hi/lo weight loads to halve transient VGPRs: ah resident for 8
    // MFMAs (ah*bh, ah*bl), then al resident for 4 (al*bh).
#define MFMA_BLOCK(WH, WL, bh, bl) do { \
        { \
            bf16x8 ah0 = ldw16(WH); \
            bf16x8 ah1 = ldw16(WH + 1024); \
            bf16x8 ah2 = ldw16(WH + 2048); \
            bf16x8 ah3 = ldw16(WH + 3072); \
            acc0 = MFMA(ah0, bh, acc0); acc0 = MFMA(ah0, bl, acc0); \
            acc1 = MFMA(ah1, bh, acc1); acc1 = MFMA(ah1, bl, acc1); \
            acc2 = MFMA(ah2, bh, acc2); acc2 = MFMA(ah2, bl, acc2); \
            acc3 = MFMA(ah3, bh, acc3); acc3 = MFMA(ah3, bl, acc3); \
        } \
        { \
            bf16x8 al0 = ldw16(WL); \
            bf16x8 al1 = ldw16(WL + 1024); \
            bf16x8 al2 = ldw16(WL + 2048); \
            bf16x8 al3 = ldw16(WL + 3072); \
            acc0 = MFMA(al0, bh, acc0); \
            acc1 = MFMA(al1, bh, acc1); \
            acc2 = MFMA(al2, bh, acc2); \
            acc3 = MFMA(al3, bh, acc3); \
        } \
    } while (0)

#define TAP(K, DYc, DXc, NDY, NDX, ISLAST) \
    { \
        /* stage ks=0: issue ks=1 gathers into gB, consume gA */ \
        gather_half<DYc, DXc>(xq1, C, gB0, gB1, gB2, gB3); \
        { \
            bf16x8 bh, bl; \
            combine_half<DYc, DXc>(C, gA0, gA1, gA2, gA3, bh, bl); \
            const unsigned short* whk = Whi + (K) * OO * CC + fragbase; \
            const unsigned short* wlk = Wlo + (K) * OO * CC + fragbase; \
            MFMA_BLOCK(whk, wlk, bh, bl); \
        } \
        /* stage ks=1: compute next coords, issue next ks=0 into gA, consume gB */ \
        { \
            TapC Cn = C; \
            if (!(ISLAST)) { \
                Cn = mk_coords<NDY, NDX>(y, xg, fy, fx, rh, rw); \
                gather_half<NDY, NDX>(xq0, Cn, gA0, gA1, gA2, gA3); \
            } \
            bf16x8 bh, bl; \
            combine_half<DYc, DXc>(C, gB0, gB1, gB2, gB3, bh, bl); \
            const unsigned short* whk = Whi + (K) * OO * CC + fragbase + 32; \
            const unsigned short* wlk = Wlo + (K) * OO * CC + fragbase + 32; \
            MFMA_BLOCK(whk, wlk, bh, bl); \
            C = Cn; \
        } \
    }

    // prologue: stage tap 0, ks=0
    C = mk_coords<-1, -1>(y, xg, fy, fx, rh, rw);
    gather_half<-1, -1>(xq0, C, gA0, gA1, gA2, gA3);

    TAP(0, -1, -1, -1,  0, 0)
    TAP(1, -1,  0, -1,  1, 0)
    TAP(2, -1,  1,  0, -1, 0)
    TAP(3,  0, -1,  0,  0, 0)
    TAP(4,  0,  0,  0,  1, 0)
    TAP(5,  0,  1,  1, -1, 0)
    TAP(6,  1, -1,  1,  0, 0)
    TAP(7,  1,  0,  1,  1, 0)
    TAP(8,  1,  1,  0,  0, 1)

#undef TAP
#undef MFMA_BLOCK
#undef MFMA

    // epilogue: o = mt*16 + quad*4 + r, pixel = p0 + wv*16 + nidx
    int px = p0 + wv * 16 + nidx;
#define EPI(MT, ACCV) do { \
        _Pragma("unroll") \
        for (int r = 0; r < 4; ++r) { \
            int o = (MT) * 16 + quad * 4 + r; \
            float v = ACCV[r] + bias[o]; \
            size_t idx = (size_t)(b * OO + o) * HWP + px; \
            if (mode == 1) v = fmaxf(v, 0.f); \
            else           v += resid[idx]; \
            out[idx] = v; \
        } \
    } while (0)
    EPI(0, acc0); EPI(1, acc1); EPI(2, acc2); EPI(3, acc3);
#undef EPI
}

// ---------------------------------------------------------------------------
extern "C" void kernel_launch(void* const* d_in, const int* in_sizes, int n_in,
                              void* d_out, int out_size, void* d_ws, size_t ws_size,
                              hipStream_t stream) {
    const float* x      = (const float*)d_in[0];
    const float* w_off1 = (const float*)d_in[1];
    const float* b_off1 = (const float*)d_in[2];
    const float* W1     = (const float*)d_in[3];
    const float* b1     = (const float*)d_in[4];
    const float* w_off2 = (const float*)d_in[5];
    const float* b_off2 = (const float*)d_in[6];
    const float* W2     = (const float*)d_in[7];
    const float* b2     = (const float*)d_in[8];
    const int*   lo_p   = (const int*)d_in[10];
    const int*   hi_p   = (const int*)d_in[11];
    float* outp = (float*)d_out;

    float* wsf = (float*)d_ws;
    float* t1  = wsf;                               // B*C*HW f32
    unsigned short* Wh1 = (unsigned short*)(t1 + (size_t)BB * CC * HWP);
    unsigned short* Wl1 = Wh1 + OO * CC * 9;        // 36864 each
    unsigned short* Wh2 = Wl1 + OO * CC * 9;
    unsigned short* Wl2 = Wh2 + OO * CC * 9;

    // 1. transpose+split both weight tensors
    wtrans_kernel<<<288, 256, 0, stream>>>(W1, W2, Wh1, Wl1, Wh2, Wl2);

    // 2. layer 1: fused offsets + arconv + relu -> t1
    arconv_kernel<<<1024, 256, 0, stream>>>(x, Wh1, Wl1, b1, w_off1, b_off1,
                                            lo_p, hi_p, nullptr, t1, 1);

    // 3. layer 2: fused offsets + arconv + residual -> out
    arconv_kernel<<<1024, 256, 0, stream>>>(t1, Wh2, Wl2, b2, w_off2, b_off2,
                                            lo_p, hi_p, x, outp, 2);
}